// Round 1
// baseline (7894.231 us; speedup 1.0000x reference)
//
#include <hip/hip_runtime.h>

#define T_LEN 1024
#define NB 64
#define NF 64
#define NU 256
#define NG 1024

typedef float f32x4 __attribute__((ext_vector_type(4)));
typedef unsigned long long u64;

__device__ __forceinline__ float sigm(float x){ return 1.0f/(1.0f + __expf(-x)); }
__device__ __forceinline__ float tanh2(float x){ return 2.0f/(1.0f + __expf(-2.0f*x)) - 1.0f; }

__device__ __forceinline__ u64 pack8(float v0,float v1,float v2,float v3,
                                     float v4,float v5,float v6,float v7){
  int lo = __builtin_amdgcn_cvt_pk_fp8_f32(v0, v1, 0, false);
  lo = __builtin_amdgcn_cvt_pk_fp8_f32(v2, v3, lo, true);
  int hi = __builtin_amdgcn_cvt_pk_fp8_f32(v4, v5, 0, false);
  hi = __builtin_amdgcn_cvt_pk_fp8_f32(v6, v7, hi, true);
  return ((u64)(unsigned)hi << 32) | (unsigned)lo;
}

// ---------------------------------------------------------------------------
// K2: fused LSTM + Dense head. 4 WGs x 512 thr; WG owns batch rows [wg*16, +16).
// Wh resident in VGPRs as fp8 MFMA B-frags (128 VGPR/thr), Wx fp8 in LDS.
// A = [x_t | h_{t-1}] fp8(x*16); B = fp8(16*W); z = acc/256 + bias.
// Wave w owns u-slice [w*32, w*32+32): n-tiles (gate gi, jj) at n=gi*256+w*32+jj*16.
// ---------------------------------------------------------------------------
__global__ __launch_bounds__(512, 2) void lstm_kernel(
    const float* __restrict__ X, const float* __restrict__ Wx,
    const float* __restrict__ Wh, const float* __restrict__ Bias,
    const float* __restrict__ Wd, const float* __restrict__ Bd,
    float* __restrict__ g_out)
{
  __shared__ unsigned char wx_lds[64*1024]; // [n][k] fp8 of 16*Wx
  __shared__ unsigned char h_lds[16*256];   // [b][u] fp8 of 16*h
  __shared__ float wd_lds[256];

  const int tid = threadIdx.x;
  const int w = tid >> 6, l = tid & 63;
  const int wg = blockIdx.x;
  const int l15 = l & 15, lhi = l >> 4;

  for (int idx = tid; idx < 64*1024; idx += 512){
    int k = idx >> 10, n = idx & 1023;
    float v = Wx[idx] * 16.f;
    int p = __builtin_amdgcn_cvt_pk_fp8_f32(v, v, 0, false);
    wx_lds[n*64 + k] = (unsigned char)(p & 0xff);
  }
  for (int idx = tid; idx < 256; idx += 512) wd_lds[idx] = Wd[idx];
  for (int idx = tid; idx < 16*256; idx += 512) h_lds[idx] = 0;

  // resident Wh B-frags: whf[kt][gi*2+jj], k = 64 + kt*32 + lhi*8 + e
  u64 whf[8][8];
  #pragma unroll
  for (int kt = 0; kt < 8; ++kt){
    #pragma unroll
    for (int gi = 0; gi < 4; ++gi){
      #pragma unroll
      for (int jj = 0; jj < 2; ++jj){
        int k0 = kt*32 + lhi*8;
        int n  = gi*256 + w*32 + jj*16 + l15;
        const float* p = Wh + (size_t)k0*1024 + n;
        whf[kt][gi*2+jj] = pack8(p[0]*16.f, p[1024]*16.f, p[2048]*16.f, p[3072]*16.f,
                                 p[4096]*16.f, p[5120]*16.f, p[6144]*16.f, p[7168]*16.f);
      }
    }
  }

  float bias_r[8];
  #pragma unroll
  for (int gi = 0; gi < 4; ++gi)
    #pragma unroll
    for (int jj = 0; jj < 2; ++jj)
      bias_r[gi*2+jj] = Bias[gi*256 + w*32 + jj*16 + l15];

  float c_r[8];
  #pragma unroll
  for (int i = 0; i < 8; ++i) c_r[i] = 0.f;
  const float bd0 = Bd[0];
  const float* xrow = X + (size_t)(wg*16 + l15)*65536; // b-row base (T*F floats)

  __syncthreads();

  for (int t = 0; t < T_LEN; ++t){
    // issue x loads early; latency hides under the 64 h-side MFMAs
    const float* xp = xrow + t*64 + lhi*8;
    float4 xa = *(const float4*)(xp);
    float4 xb = *(const float4*)(xp + 4);
    float4 xc = *(const float4*)(xp + 32);
    float4 xd = *(const float4*)(xp + 36);

    f32x4 acc[8];
    #pragma unroll
    for (int i = 0; i < 8; ++i) acc[i] = 0.f;

    #pragma unroll
    for (int kt = 2; kt < 10; ++kt){
      const u64 a = *(const u64*)(&h_lds[l15*256 + (kt-2)*32 + lhi*8]);
      #pragma unroll
      for (int gi = 0; gi < 4; ++gi)
        #pragma unroll
        for (int jj = 0; jj < 2; ++jj)
          acc[gi*2+jj] = __builtin_amdgcn_mfma_f32_16x16x32_fp8_fp8(
              (long)a, (long)whf[kt-2][gi*2+jj], acc[gi*2+jj], 0, 0, 0);
    }
    u64 ax[2];
    ax[0] = pack8(xa.x*16.f, xa.y*16.f, xa.z*16.f, xa.w*16.f,
                  xb.x*16.f, xb.y*16.f, xb.z*16.f, xb.w*16.f);
    ax[1] = pack8(xc.x*16.f, xc.y*16.f, xc.z*16.f, xc.w*16.f,
                  xd.x*16.f, xd.y*16.f, xd.z*16.f, xd.w*16.f);
    #pragma unroll
    for (int kt = 0; kt < 2; ++kt){
      const u64 a = ax[kt];
      #pragma unroll
      for (int gi = 0; gi < 4; ++gi)
        #pragma unroll
        for (int jj = 0; jj < 2; ++jj){
          const u64 bfr = *(const u64*)(&wx_lds[(gi*256 + w*32 + jj*16 + l15)*64 + kt*32 + lhi*8]);
          acc[gi*2+jj] = __builtin_amdgcn_mfma_f32_16x16x32_fp8_fp8(
              (long)a, (long)bfr, acc[gi*2+jj], 0, 0, 0);
        }
    }

    float hnew[8];
    #pragma unroll
    for (int jj = 0; jj < 2; ++jj){
      #pragma unroll
      for (int r = 0; r < 4; ++r){
        float zi = acc[0+jj][r]*(1.f/256.f) + bias_r[0+jj];
        float zf = acc[2+jj][r]*(1.f/256.f) + bias_r[2+jj];
        float zg = acc[4+jj][r]*(1.f/256.f) + bias_r[4+jj];
        float zo = acc[6+jj][r]*(1.f/256.f) + bias_r[6+jj];
        float ig = sigm(zi), fg = sigm(zf), gg = tanh2(zg), og = sigm(zo);
        float c = fg*c_r[jj*4+r] + ig*gg;
        c_r[jj*4+r] = c;
        hnew[jj*4+r] = og*tanh2(c);
      }
    }
    __syncthreads(); // all h_{t-1} reads done
    #pragma unroll
    for (int jj = 0; jj < 2; ++jj){
      #pragma unroll
      for (int r = 0; r < 4; ++r){
        int b = lhi*4 + r, u = w*32 + jj*16 + l15;
        int p = __builtin_amdgcn_cvt_pk_fp8_f32(hnew[jj*4+r]*16.f, 0.f, 0, false);
        h_lds[b*256 + u] = (unsigned char)(p & 0xff);
      }
    }
    __syncthreads(); // h_t visible

    if (w == 0){ // dense head g = h@Wd + bd, 4 lanes per batch row
      int b = l >> 2, q = l & 3;
      float s = 0.f;
      for (int u = q*64; u < q*64 + 64; ++u){
        float hv = __builtin_amdgcn_cvt_f32_fp8((int)h_lds[b*256 + u], 0);
        s = fmaf(hv, wd_lds[u], s);
      }
      s += __shfl_xor(s, 1, 64);
      s += __shfl_xor(s, 2, 64);
      if (q == 0) g_out[(wg*16 + b)*1024 + t] = s*(1.f/16.f) + bd0;
    }
  }
}

// ---------------------------------------------------------------------------
// K3: Chebyshev solves A y = e_j for j=0..127 and j=512 (stencil).
// A = Toeplitz band: a[d] = exp(-0.5*(d/10)^2), diag +0.1, half-bandwidth 64.
// Spectrum in [0.1, 25.17] -> use [0.0999, 25.3]; 128 iters -> rel err ~1e-7.
// ---------------------------------------------------------------------------
__global__ __launch_bounds__(512) void cheb_kernel(float* __restrict__ cols)
{
  const int j0 = (blockIdx.x < 128) ? blockIdx.x : 512;
  __shared__ float dpad[64 + 1024 + 64];
  __shared__ float xv[1024];
  __shared__ float rv[1024];
  __shared__ float aband[65];
  const int tid = threadIdx.x;

  if (tid < 65){ float dd = tid*0.1f; aband[tid] = expf(-0.5f*dd*dd); }
  const float lmin = 0.0999f, lmax = 25.3f;
  const float th = 0.5f*(lmax+lmin), de = 0.5f*(lmax-lmin);
  const float s1 = th/de;
  float rho = 1.f/s1;

  for (int t = tid; t < 1024; t += 512){
    float r0 = (t == j0) ? 1.f : 0.f;
    xv[t] = 0.f; rv[t] = r0; dpad[64+t] = r0/th;
  }
  if (tid < 64){ dpad[tid] = 0.f; dpad[64+1024+tid] = 0.f; }
  __syncthreads();

  for (int it = 0; it < 128; ++it){
    float ad[2];
    #pragma unroll
    for (int h = 0; h < 2; ++h){
      int t = tid + h*512;
      const float* dp = &dpad[64+t];
      float a = 1.1f * dp[0]; // aband[0] + 0.1 noise
      #pragma unroll 8
      for (int jj = 1; jj <= 64; ++jj) a = fmaf(aband[jj], dp[jj] + dp[-jj], a);
      ad[h] = a;
    }
    float rhon = 1.f/(2.f*s1 - rho);
    __syncthreads(); // matvec reads complete before d is overwritten
    #pragma unroll
    for (int h = 0; h < 2; ++h){
      int t = tid + h*512;
      float dold = dpad[64+t];
      xv[t] += dold;
      float r = rv[t] - ad[h];
      rv[t] = r;
      dpad[64+t] = rhon*rho*dold + (2.f*rhon/de)*r;
    }
    rho = rhon;
    __syncthreads();
  }
  for (int t = tid; t < 1024; t += 512) cols[(size_t)blockIdx.x*1024 + t] = xv[t];
}

// ---------------------------------------------------------------------------
// K4/K5: apply M = I - 0.1*Ainv along t, per (b, 16-col chunk), in place safe:
// WG stages its own [1024 x 16] tile in LDS, then writes only that region.
// Interior rows 128..895: 257-tap stencil (Ainv col 512). Rows <128 / >=896:
// exact dot with stored Ainv columns (persymmetric mirror for the bottom).
// ADDF: add f = g/64 (dead-attention residual).
// ---------------------------------------------------------------------------
template<int ADDF>
__global__ __launch_bounds__(256) void apply_kernel(
    const float* __restrict__ in, const float* __restrict__ cols,
    const float* __restrict__ gbuf, float* __restrict__ out)
{
  const int b  = blockIdx.x >> 2;
  const int c0 = (blockIdx.x & 3) * 16;
  __shared__ float xt[1024*16];
  __shared__ float st[257];

  const float* src = in + (size_t)b*65536 + c0;
  for (int idx = threadIdx.x; idx < 4096; idx += 256){
    int t = idx >> 2, q = idx & 3;
    *(float4*)(&xt[t*16 + q*4]) = *(const float4*)(src + t*64 + q*4);
  }
  for (int i = threadIdx.x; i < 257; i += 256) st[i] = cols[128*1024 + 384 + i];
  __syncthreads();

  float* dst = out + (size_t)b*65536 + c0;
  // interior
  for (int idx = threadIdx.x; idx < 768*16; idx += 256){
    int t = 128 + (idx >> 4), c = idx & 15;
    float a = 0.f;
    #pragma unroll 8
    for (int j = 0; j < 257; ++j) a = fmaf(st[j], xt[(t-128+j)*16 + c], a);
    float v = xt[t*16+c] - 0.1f*a;
    if (ADDF) v += gbuf[b*1024+t]*0.015625f;
    dst[t*64 + c] = v;
  }
  // boundary (top exact, bottom via persymmetry)
  for (int idx = threadIdx.x; idx < 256*16; idx += 256){
    int tb = idx >> 4, c = idx & 15;
    float a = 0.f;
    int t, tt;
    if (tb < 128){
      t = tb; tt = tb;
      for (int s = 0; s < 384; ++s) a = fmaf(cols[(size_t)tt*1024 + s], xt[s*16 + c], a);
    } else {
      t = 896 + (tb - 128); tt = 1023 - t;
      for (int s = 0; s < 384; ++s) a = fmaf(cols[(size_t)tt*1024 + s], xt[(1023-s)*16 + c], a);
    }
    float v = xt[t*16+c] - 0.1f*a;
    if (ADDF) v += gbuf[b*1024+t]*0.015625f;
    dst[t*64 + c] = v;
  }
}

// ---------------------------------------------------------------------------
extern "C" void kernel_launch(void* const* d_in, const int* in_sizes, int n_in,
                              void* d_out, int out_size, void* d_ws, size_t ws_size,
                              hipStream_t stream)
{
  const float* X    = (const float*)d_in[0];
  const float* Wx   = (const float*)d_in[1];
  const float* Wh   = (const float*)d_in[2];
  const float* Bias = (const float*)d_in[3];
  const float* Wd   = (const float*)d_in[4];
  const float* Bd   = (const float*)d_in[5];
  float* out = (float*)d_out;
  char* ws = (char*)d_ws;

  float* g    = (float*)ws;                   // 64*1024 f32 = 256KB
  float* cols = (float*)(ws + (256<<10));     // 129*1024 f32 = 516KB

  hipLaunchKernelGGL(lstm_kernel, dim3(4),   dim3(512), 0, stream,
                     X, Wx, Wh, Bias, Wd, Bd, g);
  hipLaunchKernelGGL(cheb_kernel, dim3(129), dim3(512), 0, stream, cols);
  // u = M x + f  (in place into d_out)
  hipLaunchKernelGGL((apply_kernel<1>), dim3(256), dim3(256), 0, stream, X,   cols, g, out);
  // z = M u      (in place on d_out)
  hipLaunchKernelGGL((apply_kernel<0>), dim3(256), dim3(256), 0, stream, out, cols, g, out);
}

// Round 6
// 3292.776 us; speedup vs baseline: 2.3974x; 2.3974x over previous
//
#include <hip/hip_runtime.h>

#define T_LEN 1024
#define LOG2E 1.4426950408889634f

typedef float f32x4 __attribute__((ext_vector_type(4)));
typedef unsigned long long u64;

__device__ __forceinline__ u64 pack8(float v0,float v1,float v2,float v3,
                                     float v4,float v5,float v6,float v7){
  int lo = __builtin_amdgcn_cvt_pk_fp8_f32(v0, v1, 0, false);
  lo = __builtin_amdgcn_cvt_pk_fp8_f32(v2, v3, lo, true);
  int hi = __builtin_amdgcn_cvt_pk_fp8_f32(v4, v5, 0, false);
  hi = __builtin_amdgcn_cvt_pk_fp8_f32(v6, v7, hi, true);
  return ((u64)(unsigned)hi << 32) | (unsigned)lo;
}

__device__ __forceinline__ float sigp(float y){
  // 1/(1+2^-y)
  return __builtin_amdgcn_rcpf(1.f + __builtin_amdgcn_exp2f(-y));
}

// ---------------------------------------------------------------------------
// K2: fused LSTM + Dense head, transposed MFMA orientation.
// 4 WGs x 512 thr; WG owns batch rows [wg*16, +16).
// D[row=u, col=b] = A(W^T, fp8, regs/LDS) x B([x|h]^T, fp8).
// h exchange: h_lds[kt][lhi][b][8B] — BW-floor LDS access both sides.
// Gate consts (log2e, 2log2e) folded into weight scale; bias via k=64 block.
// ---------------------------------------------------------------------------
__global__ __launch_bounds__(512, 1) void lstm_kernel(
    const float* __restrict__ X, const float* __restrict__ Wx,
    const float* __restrict__ Wh, const float* __restrict__ Bias,
    const float* __restrict__ Wd, const float* __restrict__ Bd,
    float* __restrict__ g_out)
{
  __shared__ unsigned char wx_lds[64*1024]; // A-frags of Wx: [mt][kt][lhi][row][8]
  __shared__ unsigned char h_lds[8*512];    // [kt][lhi][b][8] fp8 of 16*h
  __shared__ float g_part[8][16];

  const int tid = threadIdx.x;
  const int w = tid >> 6, l = tid & 63;
  const int l15 = l & 15, lhi = l >> 4;
  const int wg = blockIdx.x;

  // ---- prologue: Wx A-fragment fill (scale folded per gate) ----
  for (int idx = tid; idx < 65536; idx += 512){
    int f = idx >> 10, n = idx & 1023;
    float s = ((n >> 8) == 2 ? 32.f : 16.f) * LOG2E;
    float v = Wx[idx] * s;
    int p = __builtin_amdgcn_cvt_pk_fp8_f32(v, v, 0, false);
    int mt = ((n >> 8) << 4) | ((n >> 4) & 15);
    wx_lds[mt*1024 + ((f >> 5) << 9) + (((f >> 3) & 3) << 7) + ((n & 15) << 3) + (f & 7)]
        = (unsigned char)(p & 0xff);
  }
  for (int idx = tid; idx < 4096; idx += 512) h_lds[idx] = 0;

  // ---- Wh A-frags resident in VGPRs: whf[kt][m], m = g*2+jj ----
  u64 whf[8][8];
  #pragma unroll
  for (int kt = 0; kt < 8; ++kt){
    #pragma unroll
    for (int g = 0; g < 4; ++g){
      float sA = (g == 2 ? 32.f : 16.f) * LOG2E;
      #pragma unroll
      for (int jj = 0; jj < 2; ++jj){
        int n = g*256 + w*32 + jj*16 + l15;
        int k0 = kt*32 + lhi*8;
        const float* p = Wh + (size_t)k0*1024 + n;
        whf[kt][g*2+jj] = pack8(p[0]*sA, p[1024]*sA, p[2048]*sA, p[3072]*sA,
                                p[4096]*sA, p[5120]*sA, p[6144]*sA, p[7168]*sA);
      }
    }
  }
  // bias block A-frags (k=64 carries bias, B-side carries constant 16)
  u64 wxb[8];
  #pragma unroll
  for (int g = 0; g < 4; ++g){
    float sA = (g == 2 ? 32.f : 16.f) * LOG2E;
    #pragma unroll
    for (int jj = 0; jj < 2; ++jj){
      int n = g*256 + w*32 + jj*16 + l15;
      wxb[g*2+jj] = (lhi == 0) ? pack8(Bias[n]*sA, 0,0,0,0,0,0,0) : 0ull;
    }
  }
  const u64 biasb = (lhi == 0) ? 0x58ull : 0ull; // fp8(16.0) at k=64

  float wd_r[8];
  #pragma unroll
  for (int jj = 0; jj < 2; ++jj)
    #pragma unroll
    for (int r = 0; r < 4; ++r)
      wd_r[jj*4+r] = Wd[w*32 + jj*16 + lhi*4 + r];

  float c_r[8];
  #pragma unroll
  for (int i = 0; i < 8; ++i) c_r[i] = 0.f;
  const float bd0 = Bd[0];

  const float* xbase = X + (size_t)(wg*16 + l15)*65536;
  float4 xa = *(const float4*)(xbase + lhi*8);
  float4 xb = *(const float4*)(xbase + lhi*8 + 4);
  float4 xc = *(const float4*)(xbase + 32 + lhi*8);
  float4 xd = *(const float4*)(xbase + 36 + lhi*8);

  __syncthreads();

  const f32x4 z4 = {0.f, 0.f, 0.f, 0.f};
  const int hrd = lhi*128 + l15*8;
  const int hwr = w*512 + (lhi >> 1)*128 + l15*8 + (lhi & 1)*4;

  for (int t = 0; t < T_LEN; ++t){
    // h_{t-1} B-frags (conflict-floor reads)
    u64 hb[8];
    #pragma unroll
    for (int kt = 0; kt < 8; ++kt)
      hb[kt] = *(const u64*)&h_lds[kt*512 + hrd];

    f32x4 acc[8];
    #pragma unroll
    for (int m = 0; m < 8; ++m)
      acc[m] = __builtin_amdgcn_mfma_f32_16x16x32_fp8_fp8(
          (long)wxb[m], (long)biasb, z4, 0, 0, 0);

    #pragma unroll
    for (int kt = 0; kt < 8; ++kt)
      #pragma unroll
      for (int m = 0; m < 8; ++m)
        acc[m] = __builtin_amdgcn_mfma_f32_16x16x32_fp8_fp8(
            (long)whf[kt][m], (long)hb[kt], acc[m], 0, 0, 0);

    // pack x_t, then prefetch x_{t+1} into the same regs
    u64 ax0 = pack8(xa.x*16.f, xa.y*16.f, xa.z*16.f, xa.w*16.f,
                    xb.x*16.f, xb.y*16.f, xb.z*16.f, xb.w*16.f);
    u64 ax1 = pack8(xc.x*16.f, xc.y*16.f, xc.z*16.f, xc.w*16.f,
                    xd.x*16.f, xd.y*16.f, xd.z*16.f, xd.w*16.f);
    {
      int tn = (t < 1023) ? t + 1 : 1023;
      const float* xp = xbase + tn*64 + lhi*8;
      xa = *(const float4*)(xp);
      xb = *(const float4*)(xp + 4);
      xc = *(const float4*)(xp + 32);
      xd = *(const float4*)(xp + 36);
    }

    #pragma unroll
    for (int kt = 0; kt < 2; ++kt){
      const u64 bfr = kt ? ax1 : ax0;
      #pragma unroll
      for (int m = 0; m < 8; ++m){
        int mt = ((m >> 1) << 4) + w*2 + (m & 1);
        const u64 af = *(const u64*)&wx_lds[mt*1024 + (kt << 9) + (lhi << 7) + (l15 << 3)];
        acc[m] = __builtin_amdgcn_mfma_f32_16x16x32_fp8_fp8(
            (long)af, (long)bfr, acc[m], 0, 0, 0);
      }
    }

    // gate math: y = acc/256 already includes gate-specific log2e scaling
    float hsv[8];
    #pragma unroll
    for (int jj = 0; jj < 2; ++jj){
      #pragma unroll
      for (int r = 0; r < 4; ++r){
        float yi = acc[0+jj][r] * (1.f/256.f);
        float yf = acc[2+jj][r] * (1.f/256.f);
        float yg = acc[4+jj][r] * (1.f/256.f);
        float yo = acc[6+jj][r] * (1.f/256.f);
        float ig = sigp(yi);
        float fg = sigp(yf);
        float gg = 2.f*sigp(yg) - 1.f;
        float og = sigp(yo);
        float c = fmaf(fg, c_r[jj*4+r], ig*gg);
        c_r[jj*4+r] = c;
        float th = 2.f*sigp(c*(2.f*LOG2E)) - 1.f;
        hsv[jj*4+r] = og*th;
      }
    }

    // dense head partial (all lanes useful)
    float s = 0.f;
    #pragma unroll
    for (int i = 0; i < 8; ++i) s = fmaf(hsv[i], wd_r[i], s);
    s += __shfl_xor(s, 16, 64);
    s += __shfl_xor(s, 32, 64);

    __syncthreads(); // all h_{t-1} reads complete

    #pragma unroll
    for (int jj = 0; jj < 2; ++jj){
      int v0 = __builtin_amdgcn_cvt_pk_fp8_f32(hsv[jj*4+0]*16.f, hsv[jj*4+1]*16.f, 0, false);
      v0 = __builtin_amdgcn_cvt_pk_fp8_f32(hsv[jj*4+2]*16.f, hsv[jj*4+3]*16.f, v0, true);
      *(int*)&h_lds[hwr + jj*256] = v0;
    }
    if (l < 16) g_part[w][l15] = s;
    __syncthreads(); // h_t + partials visible

    if (w == 0 && l < 16){
      float gs = bd0;
      #pragma unroll
      for (int ww = 0; ww < 8; ++ww) gs += g_part[ww][l15];
      g_out[(size_t)(wg*16 + l15)*1024 + t] = gs;
    }
  }
}

// ---------------------------------------------------------------------------
// K3: Chebyshev solves A y = e_j for j=0..127 and j=512 (stencil).
// A = Toeplitz band: a[d] = exp(-0.5*(d/10)^2), diag +0.1, half-bandwidth 48.
// Spectrum in [0.1, 25.17] -> bounds [0.0999, 25.3]; 80 iters -> rel err ~5e-5.
// ---------------------------------------------------------------------------
__global__ __launch_bounds__(512) void cheb_kernel(float* __restrict__ cols)
{
  const int j0 = (blockIdx.x < 128) ? blockIdx.x : 512;
  __shared__ float dpad[64 + 1024 + 64];
  __shared__ float xv[1024];
  __shared__ float rv[1024];
  __shared__ float aband[65];
  const int tid = threadIdx.x;

  if (tid < 65){ float dd = tid*0.1f; aband[tid] = expf(-0.5f*dd*dd); }
  const float lmin = 0.0999f, lmax = 25.3f;
  const float th = 0.5f*(lmax+lmin), de = 0.5f*(lmax-lmin);
  const float s1 = th/de;
  float rho = 1.f/s1;

  for (int t = tid; t < 1024; t += 512){
    float r0 = (t == j0) ? 1.f : 0.f;
    xv[t] = 0.f; rv[t] = r0; dpad[64+t] = r0/th;
  }
  if (tid < 64){ dpad[tid] = 0.f; dpad[64+1024+tid] = 0.f; }
  __syncthreads();

  for (int it = 0; it < 80; ++it){
    float ad[2];
    #pragma unroll
    for (int h = 0; h < 2; ++h){
      int t = tid + h*512;
      const float* dp = &dpad[64+t];
      float a = 1.1f * dp[0];
      #pragma unroll 8
      for (int jj = 1; jj <= 48; ++jj) a = fmaf(aband[jj], dp[jj] + dp[-jj], a);
      ad[h] = a;
    }
    float rhon = 1.f/(2.f*s1 - rho);
    __syncthreads();
    #pragma unroll
    for (int h = 0; h < 2; ++h){
      int t = tid + h*512;
      float dold = dpad[64+t];
      xv[t] += dold;
      float r = rv[t] - ad[h];
      rv[t] = r;
      dpad[64+t] = rhon*rho*dold + (2.f*rhon/de)*r;
    }
    rho = rhon;
    __syncthreads();
  }
  for (int t = tid; t < 1024; t += 512) cols[(size_t)blockIdx.x*1024 + t] = xv[t];
}

// ---------------------------------------------------------------------------
// K4/K5: apply M = I - 0.1*Ainv along t, per (b, 16-col chunk), in-place safe.
// ---------------------------------------------------------------------------
template<int ADDF>
__global__ __launch_bounds__(256) void apply_kernel(
    const float* __restrict__ in, const float* __restrict__ cols,
    const float* __restrict__ gbuf, float* __restrict__ out)
{
  const int b  = blockIdx.x >> 2;
  const int c0 = (blockIdx.x & 3) * 16;
  __shared__ float xt[1024*16];
  __shared__ float st[257];

  const float* src = in + (size_t)b*65536 + c0;
  for (int idx = threadIdx.x; idx < 4096; idx += 256){
    int t = idx >> 2, q = idx & 3;
    *(float4*)(&xt[t*16 + q*4]) = *(const float4*)(src + t*64 + q*4);
  }
  for (int i = threadIdx.x; i < 257; i += 256) st[i] = cols[128*1024 + 384 + i];
  __syncthreads();

  float* dst = out + (size_t)b*65536 + c0;
  for (int idx = threadIdx.x; idx < 768*16; idx += 256){
    int t = 128 + (idx >> 4), c = idx & 15;
    float a = 0.f;
    #pragma unroll 8
    for (int j = 0; j < 257; ++j) a = fmaf(st[j], xt[(t-128+j)*16 + c], a);
    float v = xt[t*16+c] - 0.1f*a;
    if (ADDF) v += gbuf[b*1024+t]*0.015625f;
    dst[t*64 + c] = v;
  }
  for (int idx = threadIdx.x; idx < 256*16; idx += 256){
    int tb = idx >> 4, c = idx & 15;
    float a = 0.f;
    int t, tt;
    if (tb < 128){
      t = tb; tt = tb;
      for (int s = 0; s < 384; ++s) a = fmaf(cols[(size_t)tt*1024 + s], xt[s*16 + c], a);
    } else {
      t = 896 + (tb - 128); tt = 1023 - t;
      for (int s = 0; s < 384; ++s) a = fmaf(cols[(size_t)tt*1024 + s], xt[(1023-s)*16 + c], a);
    }
    float v = xt[t*16+c] - 0.1f*a;
    if (ADDF) v += gbuf[b*1024+t]*0.015625f;
    dst[t*64 + c] = v;
  }
}

// ---------------------------------------------------------------------------
extern "C" void kernel_launch(void* const* d_in, const int* in_sizes, int n_in,
                              void* d_out, int out_size, void* d_ws, size_t ws_size,
                              hipStream_t stream)
{
  const float* X    = (const float*)d_in[0];
  const float* Wx   = (const float*)d_in[1];
  const float* Wh   = (const float*)d_in[2];
  const float* Bias = (const float*)d_in[3];
  const float* Wd   = (const float*)d_in[4];
  const float* Bd   = (const float*)d_in[5];
  float* out = (float*)d_out;
  char* ws = (char*)d_ws;

  float* g    = (float*)ws;                   // 64*1024 f32 = 256KB
  float* cols = (float*)(ws + (256<<10));     // 129*1024 f32 = 516KB

  hipLaunchKernelGGL(lstm_kernel, dim3(4),   dim3(512), 0, stream,
                     X, Wx, Wh, Bias, Wd, Bd, g);
  hipLaunchKernelGGL(cheb_kernel, dim3(129), dim3(512), 0, stream, cols);
  hipLaunchKernelGGL((apply_kernel<1>), dim3(256), dim3(256), 0, stream, X,   cols, g, out);
  hipLaunchKernelGGL((apply_kernel<0>), dim3(256), dim3(256), 0, stream, out, cols, g, out);
}

// Round 7
// 2786.302 us; speedup vs baseline: 2.8332x; 1.1818x over previous
//
#include <hip/hip_runtime.h>

#define T_LEN 1024
#define LOG2E 1.4426950408889634f
#define SW 423.0f   // weight quant scale (safe for |W| <= 0.30)
#define SX 21.0f    // x quant scale (safe for |x| <= 6.05)

typedef int v4i __attribute__((ext_vector_type(4)));

__device__ __forceinline__ float sigp(float y){ // 1/(1+2^-y)
  return __builtin_amdgcn_rcpf(1.f + __builtin_amdgcn_exp2f(-y));
}
__device__ __forceinline__ int packq4(float a, float b, float c, float d, float s){
  int q0 = (int)rintf(a*s), q1 = (int)rintf(b*s);
  int q2 = (int)rintf(c*s), q3 = (int)rintf(d*s);
  return (q0&255) | ((q1&255)<<8) | ((q2&255)<<16) | (q3<<24);
}

// ---------------------------------------------------------------------------
// FAT kernel: blocks 0..3 = LSTM+Dense (i8 MFMA, 16 batch rows each);
// blocks 4..132 = Chebyshev column solves (run on otherwise-idle CUs).
// ---------------------------------------------------------------------------
__global__ __launch_bounds__(512, 2) void fat_kernel(
    const float* __restrict__ X, const float* __restrict__ Wx,
    const float* __restrict__ Wh, const float* __restrict__ Bias,
    const float* __restrict__ Wd, const float* __restrict__ Bd,
    float* __restrict__ g_out, float* __restrict__ colsT,
    float* __restrict__ st1)
{
  // ---- shared (sum ~154 KB; 1 WG/CU by design) ----
  __shared__ __attribute__((aligned(16))) unsigned char wx_lds[64*1024];   // Wx A-frags [mt][lane][16B]
  __shared__ __attribute__((aligned(16))) unsigned char whl_lds[64*1024];  // o-gate Wh A-frags [tile][kb][lane][16B]
  __shared__ __attribute__((aligned(16))) unsigned char h_lds[2][16][272]; // [buf][b][u pad->272B] i8 h*127
  __shared__ float g_part[2][8][16];
  // cheb
  __shared__ float cb_dpad[64 + 1024 + 64];
  __shared__ float cb_xv[1024];
  __shared__ float cb_rv[1024];
  __shared__ float cb_aband[65];

  const int tid = threadIdx.x;

  if (blockIdx.x < 4){
    // =================== LSTM + dense head ===================
    const int w = tid >> 6, l = tid & 63;
    const int l15 = l & 15, lhi = l >> 4;
    const int wg = blockIdx.x;

    // ---- prologue: Wx A-frags -> LDS ----
    for (int slot = tid; slot < 4096; slot += 512){
      int mt = slot >> 6, ln = slot & 63;
      int n = mt*16 + (ln & 15);
      const float* wp = Wx + (size_t)((ln >> 4)*16)*1024 + n;
      int* dst = (int*)&wx_lds[slot*16];
      #pragma unroll
      for (int d = 0; d < 4; ++d)
        dst[d] = packq4(wp[(d*4+0)*1024], wp[(d*4+1)*1024],
                        wp[(d*4+2)*1024], wp[(d*4+3)*1024], SW);
    }
    // ---- o-gate Wh A-frags -> LDS (saves 32 VGPR) ----
    for (int slot = tid; slot < 4096; slot += 512){
      int tile = slot >> 8, kb = (slot >> 6) & 3, ln = slot & 63;
      int n = 768 + (tile >> 1)*32 + (tile & 1)*16 + (ln & 15);
      const float* wp = Wh + (size_t)(kb*64 + (ln >> 4)*16)*1024 + n;
      int* dst = (int*)&whl_lds[((tile*4 + kb)*64 + ln)*16];
      #pragma unroll
      for (int d = 0; d < 4; ++d)
        dst[d] = packq4(wp[(d*4+0)*1024], wp[(d*4+1)*1024],
                        wp[(d*4+2)*1024], wp[(d*4+3)*1024], SW);
    }
    // ---- zero both h buffers ----
    for (int idx = tid; idx < 2176; idx += 512) ((int*)h_lds)[idx] = 0;

    // ---- Wh A-frags (gates i,f,g) resident in VGPRs ----
    v4i whf[4][6];
    #pragma unroll
    for (int m = 0; m < 6; ++m){
      int g = m >> 1, jj = m & 1;
      int n = g*256 + w*32 + jj*16 + l15;
      #pragma unroll
      for (int kb = 0; kb < 4; ++kb){
        const float* wp = Wh + (size_t)(kb*64 + lhi*16)*1024 + n;
        v4i f;
        #pragma unroll
        for (int d = 0; d < 4; ++d)
          f[d] = packq4(wp[(d*4+0)*1024], wp[(d*4+1)*1024],
                        wp[(d*4+2)*1024], wp[(d*4+3)*1024], SW);
        whf[kb][m] = f;
      }
    }
    // bias A-bytes (k-block 5, k_local==0) + B one-hot 127
    int ab0[8];
    #pragma unroll
    for (int m = 0; m < 8; ++m){
      int g = m >> 1, jj = m & 1;
      int n = g*256 + w*32 + jj*16 + l15;
      ab0[m] = (lhi == 0) ? ((int)rintf(Bias[n]*SW) & 255) : 0;
    }
    v4i bb = { (lhi == 0) ? 127 : 0, 0, 0, 0 };
    const v4i zero4 = {0,0,0,0};

    float wd_r[8];
    #pragma unroll
    for (int jj = 0; jj < 2; ++jj)
      #pragma unroll
      for (int r = 0; r < 4; ++r)
        wd_r[jj*4+r] = Wd[w*32 + jj*16 + lhi*4 + r];

    float c_r[8];
    #pragma unroll
    for (int i = 0; i < 8; ++i) c_r[i] = 0.f;
    const float bd0 = Bd[0];
    const float cHs = LOG2E/(SW*127.f);
    const float cXs = LOG2E/(SW*SX);

    const float* xrow = X + (size_t)(wg*16 + l15)*65536 + lhi*16;
    float4 xf0 = *(const float4*)(xrow + 0);
    float4 xf1 = *(const float4*)(xrow + 4);
    float4 xf2 = *(const float4*)(xrow + 8);
    float4 xf3 = *(const float4*)(xrow + 12);
    v4i xq;
    xq[0] = packq4(xf0.x, xf0.y, xf0.z, xf0.w, SX);
    xq[1] = packq4(xf1.x, xf1.y, xf1.z, xf1.w, SX);
    xq[2] = packq4(xf2.x, xf2.y, xf2.z, xf2.w, SX);
    xq[3] = packq4(xf3.x, xf3.y, xf3.z, xf3.w, SX);
    xf0 = *(const float4*)(xrow + 64 + 0);
    xf1 = *(const float4*)(xrow + 64 + 4);
    xf2 = *(const float4*)(xrow + 64 + 8);
    xf3 = *(const float4*)(xrow + 64 + 12);

    __syncthreads();

    int p = 0;
    for (int t = 0; t < T_LEN; ++t){
      v4i accH[8], accX[8];
      // bias block
      #pragma unroll
      for (int m = 0; m < 8; ++m){
        v4i ab = { ab0[m], 0, 0, 0 };
        accH[m] = __builtin_amdgcn_mfma_i32_16x16x64_i8(ab, bb, zero4, 0, 0, 0);
      }
      // h blocks (K=256)
      #pragma unroll
      for (int kb = 0; kb < 4; ++kb){
        v4i hbk = *(const v4i*)&h_lds[p][l15][kb*64 + lhi*16];
        #pragma unroll
        for (int m = 0; m < 6; ++m)
          accH[m] = __builtin_amdgcn_mfma_i32_16x16x64_i8(whf[kb][m], hbk, accH[m], 0, 0, 0);
        #pragma unroll
        for (int m = 6; m < 8; ++m){
          v4i wf = *(const v4i*)&whl_lds[(((w*2 + (m&1))*4 + kb)*64 + l)*16];
          accH[m] = __builtin_amdgcn_mfma_i32_16x16x64_i8(wf, hbk, accH[m], 0, 0, 0);
        }
      }
      // x block (K=64)
      #pragma unroll
      for (int m = 0; m < 8; ++m){
        int mt = (m >> 1)*16 + w*2 + (m & 1);
        v4i wxf = *(const v4i*)&wx_lds[(mt*64 + l)*16];
        accX[m] = __builtin_amdgcn_mfma_i32_16x16x64_i8(wxf, xq, zero4, 0, 0, 0);
      }

      // pack x(t+1), prefetch x(t+2)
      v4i xqn;
      xqn[0] = packq4(xf0.x, xf0.y, xf0.z, xf0.w, SX);
      xqn[1] = packq4(xf1.x, xf1.y, xf1.z, xf1.w, SX);
      xqn[2] = packq4(xf2.x, xf2.y, xf2.z, xf2.w, SX);
      xqn[3] = packq4(xf3.x, xf3.y, xf3.z, xf3.w, SX);
      {
        int tn = (t < 1022) ? t + 2 : 1023;
        const float* xp = xrow + (size_t)tn*64;
        xf0 = *(const float4*)(xp + 0);
        xf1 = *(const float4*)(xp + 4);
        xf2 = *(const float4*)(xp + 8);
        xf3 = *(const float4*)(xp + 12);
      }

      // gates (y pre-scaled by log2e; g-gate by 2log2e)
      float hsv[8];
      #pragma unroll
      for (int jj = 0; jj < 2; ++jj){
        #pragma unroll
        for (int r = 0; r < 4; ++r){
          float yi = (float)accH[0+jj][r]*cHs      + (float)accX[0+jj][r]*cXs;
          float yf = (float)accH[2+jj][r]*cHs      + (float)accX[2+jj][r]*cXs;
          float yg = (float)accH[4+jj][r]*(2.f*cHs)+ (float)accX[4+jj][r]*(2.f*cXs);
          float yo = (float)accH[6+jj][r]*cHs      + (float)accX[6+jj][r]*cXs;
          float ig = sigp(yi);
          float fg = sigp(yf);
          float gg = 2.f*sigp(yg) - 1.f;
          float og = sigp(yo);
          float c = fmaf(fg, c_r[jj*4+r], ig*gg);
          c_r[jj*4+r] = c;
          float th = 2.f*sigp(c*(2.f*LOG2E)) - 1.f;
          hsv[jj*4+r] = og*th;
        }
      }

      // dense head partial
      float s = 0.f;
      #pragma unroll
      for (int i = 0; i < 8; ++i) s = fmaf(hsv[i], wd_r[i], s);
      s += __shfl_xor(s, 16, 64);
      s += __shfl_xor(s, 32, 64);

      // write h_t to other buffer (i8, conflict-free via 272B row pitch)
      #pragma unroll
      for (int jj = 0; jj < 2; ++jj){
        int dw = packq4(hsv[jj*4+0], hsv[jj*4+1], hsv[jj*4+2], hsv[jj*4+3], 127.f);
        *(int*)&h_lds[p^1][l15][(w*2+jj)*16 + lhi*4] = dw;
      }
      if (l < 16) g_part[p][w][l15] = s;
      xq = xqn;

      __syncthreads();

      if (w == 0 && l < 16){
        float gs = bd0;
        #pragma unroll
        for (int ww = 0; ww < 8; ++ww) gs += g_part[p][ww][l15];
        g_out[(size_t)(wg*16 + l15)*1024 + t] = gs;
      }
      p ^= 1;
    }
  } else {
    // =================== Chebyshev column solves ===================
    const int cidx = blockIdx.x - 4;          // 0..128
    const int j0 = (cidx < 128) ? cidx : 512;

    if (tid < 65){ float dd = tid*0.1f; cb_aband[tid] = expf(-0.5f*dd*dd); }
    const float lmin = 0.0999f, lmax = 25.3f;
    const float th = 0.5f*(lmax+lmin), de = 0.5f*(lmax-lmin);
    const float s1 = th/de;
    float rho = 1.f/s1;

    for (int t = tid; t < 1024; t += 512){
      float r0 = (t == j0) ? 1.f : 0.f;
      cb_xv[t] = 0.f; cb_rv[t] = r0; cb_dpad[64+t] = r0/th;
    }
    if (tid < 64){ cb_dpad[tid] = 0.f; cb_dpad[64+1024+tid] = 0.f; }
    __syncthreads();

    for (int it = 0; it < 80; ++it){
      float ad[2];
      #pragma unroll
      for (int h = 0; h < 2; ++h){
        int t = tid + h*512;
        const float* dp = &cb_dpad[64+t];
        float a = 1.1f * dp[0];
        #pragma unroll 8
        for (int jj = 1; jj <= 48; ++jj) a = fmaf(cb_aband[jj], dp[jj] + dp[-jj], a);
        ad[h] = a;
      }
      float rhon = 1.f/(2.f*s1 - rho);
      __syncthreads();
      #pragma unroll
      for (int h = 0; h < 2; ++h){
        int t = tid + h*512;
        float dold = cb_dpad[64+t];
        cb_xv[t] += dold;
        float r = cb_rv[t] - ad[h];
        cb_rv[t] = r;
        cb_dpad[64+t] = rhon*rho*dold + (2.f*rhon/de)*r;
      }
      rho = rhon;
      __syncthreads();
    }
    if (cidx == 128){
      for (int i = tid; i < 257; i += 512) st1[i] = cb_xv[384 + i];
    } else {
      for (int s = tid; s < 1024; s += 512) colsT[(size_t)s*128 + cidx] = cb_xv[s];
    }
  }
}

// ---------------------------------------------------------------------------
// apply: out = in - 0.1*Ainv*in (+ g/64 if ADDF), along t per (b, 16-col chunk).
// Interior rows 128..895: slide-8 register-window 257-tap stencil.
// Boundary 2x128 rows: s-outer dot against transposed exact columns.
// In-place safe (tile fully staged to LDS first).
// ---------------------------------------------------------------------------
template<int ADDF>
__global__ __launch_bounds__(256) void apply_kernel(
    const float* __restrict__ in, const float* __restrict__ colsT,
    const float* __restrict__ st1, const float* __restrict__ gbuf,
    float* __restrict__ out)
{
  const int b  = blockIdx.x >> 2;
  const int c0 = (blockIdx.x & 3) * 16;
  __shared__ float xt[1040*17];   // [t][c] pitch 17 (bank-spread)
  __shared__ float stc[260];

  const float* src = in + (size_t)b*65536 + c0;
  for (int idx = threadIdx.x; idx < 16384; idx += 256){
    int t = idx >> 4, c = idx & 15;
    xt[t*17 + c] = src[t*64 + c];
  }
  for (int i = threadIdx.x; i < 257; i += 256) stc[i] = st1[i];
  __syncthreads();

  float* dst = out + (size_t)b*65536 + c0;

  // ---- interior: t in [128, 896), slide-8 ----
  for (int task = threadIdx.x; task < 1536; task += 256){
    int tb = task >> 4, c = task & 15;
    int base = tb*8;                       // out rows 128+base .. +8
    float acc[8];
    #pragma unroll
    for (int i = 0; i < 8; ++i) acc[i] = 0.f;
    float wreg[16];
    #pragma unroll
    for (int q = 0; q < 16; ++q) wreg[q] = xt[(base+q)*17 + c];

    for (int jo = 0; jo < 256; jo += 8){
      float sv[8];
      *(float4*)(sv)   = *(const float4*)&stc[jo];
      *(float4*)(sv+4) = *(const float4*)&stc[jo+4];
      #pragma unroll
      for (int jj = 0; jj < 8; ++jj){
        float s = sv[jj];
        #pragma unroll
        for (int i = 0; i < 8; ++i) acc[i] = fmaf(s, wreg[jj+i], acc[i]);
      }
      #pragma unroll
      for (int q = 0; q < 8; ++q) wreg[q] = wreg[q+8];
      #pragma unroll
      for (int q = 0; q < 8; ++q) wreg[8+q] = xt[(base+jo+16+q)*17 + c];
    }
    #pragma unroll
    for (int i = 0; i < 8; ++i) acc[i] = fmaf(stc[256], wreg[i], acc[i]);

    #pragma unroll
    for (int i = 0; i < 8; ++i){
      int t = 128 + base + i;
      float v = xt[t*17 + c] - 0.1f*acc[i];
      if (ADDF) v += gbuf[b*1024 + t]*0.015625f;
      dst[t*64 + c] = v;
    }
  }

  // ---- boundary: t in [0,128) and [896,1024), exact columns ----
  for (int task = threadIdx.x; task < 512; task += 256){
    int tb = task >> 4, c = task & 15;
    float acc[8];
    #pragma unroll
    for (int i = 0; i < 8; ++i) acc[i] = 0.f;
    if (tb < 16){
      int t0 = tb*8;
      for (int s = 0; s < 384; ++s){
        float xv = xt[s*17 + c];
        float4 cv0 = *(const float4*)&colsT[(size_t)s*128 + t0];
        float4 cv1 = *(const float4*)&colsT[(size_t)s*128 + t0 + 4];
        acc[0] = fmaf(cv0.x, xv, acc[0]); acc[1] = fmaf(cv0.y, xv, acc[1]);
        acc[2] = fmaf(cv0.z, xv, acc[2]); acc[3] = fmaf(cv0.w, xv, acc[3]);
        acc[4] = fmaf(cv1.x, xv, acc[4]); acc[5] = fmaf(cv1.y, xv, acc[5]);
        acc[6] = fmaf(cv1.z, xv, acc[6]); acc[7] = fmaf(cv1.w, xv, acc[7]);
      }
      #pragma unroll
      for (int i = 0; i < 8; ++i){
        int t = t0 + i;
        float v = xt[t*17 + c] - 0.1f*acc[i];
        if (ADDF) v += gbuf[b*1024 + t]*0.015625f;
        dst[t*64 + c] = v;
      }
    } else {
      int t0 = 896 + (tb - 16)*8;
      int ttb = 1016 - t0;                 // = 1023-t0-7
      for (int s = 0; s < 384; ++s){
        float xv = xt[(1023 - s)*17 + c];
        float4 cv0 = *(const float4*)&colsT[(size_t)s*128 + ttb];
        float4 cv1 = *(const float4*)&colsT[(size_t)s*128 + ttb + 4];
        // acc[i] pairs with cv[7-i]
        acc[7] = fmaf(cv0.x, xv, acc[7]); acc[6] = fmaf(cv0.y, xv, acc[6]);
        acc[5] = fmaf(cv0.z, xv, acc[5]); acc[4] = fmaf(cv0.w, xv, acc[4]);
        acc[3] = fmaf(cv1.x, xv, acc[3]); acc[2] = fmaf(cv1.y, xv, acc[2]);
        acc[1] = fmaf(cv1.z, xv, acc[1]); acc[0] = fmaf(cv1.w, xv, acc[0]);
      }
      #pragma unroll
      for (int i = 0; i < 8; ++i){
        int t = t0 + i;
        float v = xt[t*17 + c] - 0.1f*acc[i];
        if (ADDF) v += gbuf[b*1024 + t]*0.015625f;
        dst[t*64 + c] = v;
      }
    }
  }
}

// ---------------------------------------------------------------------------
extern "C" void kernel_launch(void* const* d_in, const int* in_sizes, int n_in,
                              void* d_out, int out_size, void* d_ws, size_t ws_size,
                              hipStream_t stream)
{
  const float* X    = (const float*)d_in[0];
  const float* Wx   = (const float*)d_in[1];
  const float* Wh   = (const float*)d_in[2];
  const float* Bias = (const float*)d_in[3];
  const float* Wd   = (const float*)d_in[4];
  const float* Bd   = (const float*)d_in[5];
  float* out = (float*)d_out;
  char* ws = (char*)d_ws;

  float* g     = (float*)ws;                    // 64*1024 f32 = 256KB
  float* colsT = (float*)(ws + (256<<10));      // 1024*128 f32 = 512KB (transposed cols)
  float* st1   = (float*)(ws + (768<<10));      // 257 f32 stencil

  hipLaunchKernelGGL(fat_kernel, dim3(133), dim3(512), 0, stream,
                     X, Wx, Wh, Bias, Wd, Bd, g, colsT, st1);
  hipLaunchKernelGGL((apply_kernel<1>), dim3(256), dim3(256), 0, stream,
                     X, colsT, st1, g, out);
  hipLaunchKernelGGL((apply_kernel<0>), dim3(256), dim3(256), 0, stream,
                     out, colsT, st1, g, out);
}